// Round 6
// baseline (227.406 us; speedup 1.0000x reference)
//
#include <hip/hip_runtime.h>

#define T_  4
#define B_  2
#define C_  384
#define L_  1024
#define H_  8
#define C2_ 768
#define S_  (B_*C_*L_)

typedef __attribute__((ext_vector_type(8))) short short8;
typedef __attribute__((ext_vector_type(4))) float floatx4;
typedef __attribute__((ext_vector_type(16))) float floatx16;

__device__ __forceinline__ unsigned bf16_rne(float v) {
    unsigned u = __float_as_uint(v);
    u += 0x7FFFu + ((u >> 16) & 1u);
    return u >> 16;
}
__device__ __forceinline__ float bf16_to_f(unsigned h) { return __uint_as_float(h << 16); }
__device__ __forceinline__ void split3(float v, unsigned& hi, unsigned& mi, unsigned& lo) {
    hi = bf16_rne(v);
    float r1 = v - bf16_to_f(hi);
    mi = bf16_rne(r1);
    float r2 = r1 - bf16_to_f(mi);
    lo = bf16_rne(r2);
}

// ==== K1+K0 merged: blocks 0-191 run the xs scan; blocks 192-623 split both
// fp32 weight tensors into 3 bf16 planes. Independent work, one launch.
__global__ __launch_bounds__(256) void scan_and_split(
    const float* __restrict__ src, unsigned short* __restrict__ dstT,
    const float* __restrict__ Wa, int n4a,
    unsigned short* __restrict__ hia, unsigned short* __restrict__ mia,
    unsigned short* __restrict__ loa,
    const float* __restrict__ Wb, int n4b,
    unsigned short* __restrict__ hib, unsigned short* __restrict__ mib,
    unsigned short* __restrict__ lob) {
    __shared__ unsigned short tile[64][72];
    const int tid = threadIdx.x;
    if (blockIdx.x >= 192) {
        // ---- weight split branch (no LDS use) ----
        int i = (blockIdx.x - 192) * 256 + tid;
        const float* W; unsigned short *hi, *mi, *lo;
        if (i < n4a) { W = Wa; hi = hia; mi = mia; lo = loa; }
        else {
            i -= n4a;
            if (i >= n4b) return;
            W = Wb; hi = hib; mi = mib; lo = lob;
        }
        float4 v = ((const float4*)W)[i];
        float vv[4] = {v.x, v.y, v.z, v.w};
        union { unsigned short us[4]; uint2 u2; } h, m, l;
#pragma unroll
        for (int e = 0; e < 4; e++) {
            unsigned hh, mm, ll; split3(vv[e], hh, mm, ll);
            h.us[e] = (unsigned short)hh; m.us[e] = (unsigned short)mm; l.us[e] = (unsigned short)ll;
        }
        ((uint2*)hi)[i] = h.u2; ((uint2*)mi)[i] = m.u2; ((uint2*)lo)[i] = l.u2;
        return;
    }
    // ---- scan branch: job = blockIdx.x in [0,192) ----
    const int job = blockIdx.x;
    const int l0 = (job & 15) * 64;
    const int c0 = ((job >> 4) % 6) * 64;
    const int b  = job / 96;
    const int row = tid >> 2, seg = tid & 3;
    float mem[16], sp[16];
#pragma unroll
    for (int e = 0; e < 16; e++) { mem[e] = 0.f; sp[e] = 0.f; }
    for (int t = 0; t < T_; t++) {
        const size_t base = ((size_t)((t*B_ + b)*C_ + c0 + row))*L_ + l0 + seg*16;
#pragma unroll
        for (int qq = 0; qq < 4; qq++) {
            float4 v = *(const float4*)(src + base + qq*4);
            float vv[4] = {v.x, v.y, v.z, v.w};
            unsigned bs[4];
#pragma unroll
            for (int s = 0; s < 4; s++) {
                int e = qq*4 + s;
                mem[e] = mem[e]*0.25f*(1.f - sp[e]) + vv[s];
                bool sb = mem[e] > 0.5f;
                sp[e] = sb ? 1.f : 0.f;
                bs[s] = sb ? 0x3F80u : 0u;
            }
            *(unsigned*)&tile[row][seg*16 + qq*4]     = bs[0] | (bs[1] << 16);
            *(unsigned*)&tile[row][seg*16 + qq*4 + 2] = bs[2] | (bs[3] << 16);
        }
        __syncthreads();
        {
            const int lr = tid >> 2, cs = tid & 3;
#pragma unroll
            for (int sub = 0; sub < 2; sub++) {
                unsigned wv[4];
#pragma unroll
                for (int p = 0; p < 4; p++) {
                    unsigned e0 = tile[cs*16 + sub*8 + p*2][lr];
                    unsigned e1 = tile[cs*16 + sub*8 + p*2 + 1][lr];
                    wv[p] = e0 | (e1 << 16);
                }
                uint4 o; o.x = wv[0]; o.y = wv[1]; o.z = wv[2]; o.w = wv[3];
                *(uint4*)(dstT + ((size_t)(t*B_ + b)*L_ + l0 + lr)*C_ + c0 + cs*16 + sub*8) = o;
            }
        }
        __syncthreads();
    }
}

// ============ K5: mem_update scan over T + bf16 spike transpose ============
__global__ __launch_bounds__(256) void scan_transpose(const float* __restrict__ src,
                                                      unsigned short* __restrict__ dstT) {
    __shared__ unsigned short tile[64][72];
    const int tid = threadIdx.x;
    const int l0 = blockIdx.x * 64, c0 = blockIdx.y * 64, b = blockIdx.z;
    const int row = tid >> 2, seg = tid & 3;
    float mem[16], sp[16];
#pragma unroll
    for (int e = 0; e < 16; e++) { mem[e] = 0.f; sp[e] = 0.f; }
    for (int t = 0; t < T_; t++) {
        const size_t base = ((size_t)((t*B_ + b)*C_ + c0 + row))*L_ + l0 + seg*16;
#pragma unroll
        for (int qq = 0; qq < 4; qq++) {
            float4 v = *(const float4*)(src + base + qq*4);
            float vv[4] = {v.x, v.y, v.z, v.w};
            unsigned bs[4];
#pragma unroll
            for (int s = 0; s < 4; s++) {
                int e = qq*4 + s;
                mem[e] = mem[e]*0.25f*(1.f - sp[e]) + vv[s];
                bool sb = mem[e] > 0.5f;
                sp[e] = sb ? 1.f : 0.f;
                bs[s] = sb ? 0x3F80u : 0u;
            }
            *(unsigned*)&tile[row][seg*16 + qq*4]     = bs[0] | (bs[1] << 16);
            *(unsigned*)&tile[row][seg*16 + qq*4 + 2] = bs[2] | (bs[3] << 16);
        }
        __syncthreads();
        {
            const int lr = tid >> 2, cs = tid & 3;
#pragma unroll
            for (int sub = 0; sub < 2; sub++) {
                unsigned wv[4];
#pragma unroll
                for (int p = 0; p < 4; p++) {
                    unsigned e0 = tile[cs*16 + sub*8 + p*2][lr];
                    unsigned e1 = tile[cs*16 + sub*8 + p*2 + 1][lr];
                    wv[p] = e0 | (e1 << 16);
                }
                uint4 o; o.x = wv[0]; o.y = wv[1]; o.z = wv[2]; o.w = wv[3];
                *(uint4*)(dstT + ((size_t)(t*B_ + b)*L_ + l0 + lr)*C_ + c0 + cs*16 + sub*8) = o;
            }
        }
        __syncthreads();
    }
}

// ============ K2: y = BN1(W @ xs) via MFMA, 96m x 64l tile, aliased LDS ====
__global__ __launch_bounds__(256) void gemm1_mfma(
    const unsigned short* __restrict__ whi, const unsigned short* __restrict__ wmi,
    const unsigned short* __restrict__ wlo, const unsigned short* __restrict__ xsT,
    const float* __restrict__ g, const float* __restrict__ be,
    const float* __restrict__ mn, const float* __restrict__ vr,
    unsigned short* __restrict__ y1hi, unsigned short* __restrict__ y1mi,
    unsigned short* __restrict__ y1lo,
    unsigned short* __restrict__ y2hi, unsigned short* __restrict__ y2mi,
    unsigned short* __restrict__ y2lo) {
    __shared__ unsigned short smem[14080];
    const int tid = threadIdx.x;
    const int flat = blockIdx.x;
    const int tb = flat & 7;
    const int ii = flat >> 3;
    const int mt = ii >> 4, lt = ii & 15;
    const int l0 = lt * 64;
    const int w = tid >> 6, lane = tid & 63;
    const int q = lane >> 4, n15 = lane & 15;
    const int mw = (w & 1) * 48, lw = (w >> 1) * 32;

    floatx4 acc[3][2];
#pragma unroll
    for (int i = 0; i < 3; i++)
#pragma unroll
        for (int j = 0; j < 2; j++) acc[i][j] = (floatx4){0.f,0.f,0.f,0.f};

    for (int ck = 0; ck < C_; ck += 32) {
#pragma unroll
        for (int p = 0; p < 3; p++) {
            const unsigned short* wp = p == 0 ? whi : p == 1 ? wmi : wlo;
            unsigned short* ap = smem + p*3840;
            for (int s = tid; s < 384; s += 256) {
                int r = s >> 2, c = s & 3;
                *(uint4*)&ap[r*40 + c*8] = *(const uint4*)(wp + (size_t)(mt*96 + r)*C_ + ck + c*8);
            }
        }
        {
            int r = tid >> 2, c = tid & 3;
            *(uint4*)&smem[11520 + r*40 + c*8] =
                *(const uint4*)(xsT + ((size_t)tb*L_ + l0 + r)*C_ + ck + c*8);
        }
        __syncthreads();
        short8 bb[2];
#pragma unroll
        for (int in = 0; in < 2; in++)
            bb[in] = *(short8*)&smem[11520 + (lw + in*16 + n15)*40 + q*8];
#pragma unroll
        for (int im = 0; im < 3; im++) {
            short8 ah = *(short8*)&smem[       (mw + im*16 + n15)*40 + q*8];
            short8 am = *(short8*)&smem[3840 + (mw + im*16 + n15)*40 + q*8];
            short8 al = *(short8*)&smem[7680 + (mw + im*16 + n15)*40 + q*8];
#pragma unroll
            for (int in = 0; in < 2; in++) {
                acc[im][in] = __builtin_amdgcn_mfma_f32_16x16x32_bf16(ah, bb[in], acc[im][in], 0,0,0);
                acc[im][in] = __builtin_amdgcn_mfma_f32_16x16x32_bf16(am, bb[in], acc[im][in], 0,0,0);
                acc[im][in] = __builtin_amdgcn_mfma_f32_16x16x32_bf16(al, bb[in], acc[im][in], 0,0,0);
            }
        }
        __syncthreads();
    }

#pragma unroll
    for (int im = 0; im < 3; im++)
#pragma unroll
        for (int r = 0; r < 4; r++) {
            int o = mt*96 + mw + im*16 + q*4 + r;
            float inv = g[o] / sqrtf(vr[o] + 1e-5f);
            float sh = be[o] - mn[o]*inv;
#pragma unroll
            for (int in = 0; in < 2; in++)
                acc[im][in][r] = acc[im][in][r]*inv + sh;
        }
    const bool isY1 = ((w & 1) == 0);
#pragma unroll
    for (int p = 0; p < 3; p++) {
        if (isY1) {
#pragma unroll
            for (int im = 0; im < 3; im++)
#pragma unroll
                for (int in = 0; in < 2; in++) {
                    union { unsigned short us[4]; uint2 u2; } pk;
#pragma unroll
                    for (int r = 0; r < 4; r++) {
                        unsigned hh = bf16_rne(acc[im][in][r]);
                        pk.us[r] = (unsigned short)hh;
                        acc[im][in][r] -= bf16_to_f(hh);
                    }
                    *(uint2*)&smem[(lw + in*16 + n15)*56 + im*16 + q*4] = pk.u2;
                }
        } else {
#pragma unroll
            for (int im = 0; im < 3; im++)
#pragma unroll
                for (int in = 0; in < 2; in++)
#pragma unroll
                    for (int r = 0; r < 4; r++) {
                        unsigned hh = bf16_rne(acc[im][in][r]);
                        smem[3584 + (im*16 + q*4 + r)*72 + lw + in*16 + n15] = (unsigned short)hh;
                        acc[im][in][r] -= bf16_to_f(hh);
                    }
        }
        __syncthreads();
        unsigned short* y1p = p == 0 ? y1hi : p == 1 ? y1mi : y1lo;
        unsigned short* y2p = p == 0 ? y2hi : p == 1 ? y2mi : y2lo;
        for (int s = tid; s < 384; s += 256) {
            int r1 = s / 6, c8 = s % 6;
            *(uint4*)(y1p + (((size_t)tb*H_ + mt)*L_ + l0 + r1)*48 + c8*8) =
                *(uint4*)&smem[r1*56 + c8*8];
        }
        for (int s = tid; s < 384; s += 256) {
            int cr = s >> 3, lq = s & 7;
            *(uint4*)(y2p + ((size_t)tb*C_ + mt*48 + cr)*L_ + l0 + lq*8) =
                *(uint4*)&smem[3584 + cr*72 + lq*8];
        }
        __syncthreads();
    }
}

// ============ K3: attn = y1^T @ xr (32x32x16 MFMA, K=48 exact) =============
// 64l x 128m tile, grid 2048 XCD-swizzled. NO LDS, NO BARRIERS: the staged
// tiles had zero reuse (each element read by exactly one lane-pair), so all
// fragments load straight global->VGPR. bits words assembled via shfl_xor
// across halves (disjoint bit positions) and stored directly (exclusive
// ownership per block -> plain store, no atomics).
__global__ __launch_bounds__(256, 4) void attn_spike_mfma(
    const unsigned short* __restrict__ y1hi, const unsigned short* __restrict__ y1mi,
    const unsigned short* __restrict__ y1lo, const unsigned short* __restrict__ xsT,
    unsigned* __restrict__ bits) {
    const int tid = threadIdx.x;
    const int flat = blockIdx.x;
    const int xcd = flat & 7;
    const int ii = flat >> 3;            // 0..255
    const int bh = xcd*2 + (ii >> 7);
    const int rr = ii & 127;
    const int b = bh >> 3, h = bh & 7;
    const int lbase = (rr >> 3) * 64;    // 16 l-tiles
    const int mbase = (rr & 7) * 128;    // 8 m-tiles
    const int w = tid >> 6, lane = tid & 63;
    const int l31 = lane & 31, half = lane >> 5;
    const int mrow = mbase + w*32 + l31;

    float mem[2][16];
#pragma unroll
    for (int il = 0; il < 2; il++)
#pragma unroll
        for (int r = 0; r < 16; r++) mem[il][r] = 0.f;

    for (int t = 0; t < T_; t++) {
        const int tb = t*B_ + b;
        const unsigned short* ya_hi = y1hi + (((size_t)tb*H_ + h)*L_ + lbase)*48;
        const unsigned short* ya_mi = y1mi + (((size_t)tb*H_ + h)*L_ + lbase)*48;
        const unsigned short* ya_lo = y1lo + (((size_t)tb*H_ + h)*L_ + lbase)*48;
        const unsigned short* xrow  = xsT + ((size_t)tb*L_ + mrow)*C_ + h*48;

        // B fragments: this lane's m-row, 3 k-slices (16B each)
        short8 bb[3];
#pragma unroll
        for (int ks = 0; ks < 3; ks++)
            bb[ks] = *(const short8*)(xrow + ks*16 + half*8);

        floatx16 acc[2];
#pragma unroll
        for (int il = 0; il < 2; il++)
#pragma unroll
            for (int r = 0; r < 16; r++) acc[il][r] = 0.f;

#pragma unroll
        for (int ks = 0; ks < 3; ks++) {
            const int kcol = ks*16 + half*8;
#pragma unroll
            for (int il = 0; il < 2; il++) {
                const int aoff = (il*32 + l31)*48 + kcol;
                short8 ah = *(const short8*)(ya_hi + aoff);
                short8 am = *(const short8*)(ya_mi + aoff);
                short8 al = *(const short8*)(ya_lo + aoff);
                acc[il] = __builtin_amdgcn_mfma_f32_32x32x16_bf16(ah, bb[ks], acc[il], 0,0,0);
                acc[il] = __builtin_amdgcn_mfma_f32_32x32x16_bf16(am, bb[ks], acc[il], 0,0,0);
                acc[il] = __builtin_amdgcn_mfma_f32_32x32x16_bf16(al, bb[ks], acc[il], 0,0,0);
            }
        }

        unsigned wds[2];
#pragma unroll
        for (int il = 0; il < 2; il++) {
            unsigned word = 0;
#pragma unroll
            for (int r = 0; r < 16; r++) {
                float m = (mem[il][r] > 0.5f ? 0.f : mem[il][r]*0.25f) + acc[il][r];
                mem[il][r] = m;
                int lloc = (r & 3) + 8*(r >> 2) + 4*half;
                word |= (m > 0.5f) ? (1u << lloc) : 0u;
            }
            wds[il] = word;
        }
        // halves hold disjoint bit positions: OR across the 32-lane split
        unsigned f0 = wds[0] | __shfl_xor(wds[0], 32);
        unsigned f1 = wds[1] | __shfl_xor(wds[1], 32);
        if (half == 0) {
            uint2 o; o.x = f0; o.y = f1;
            *(uint2*)(bits + ((size_t)(tb*H_ + h)*L_ + mrow)*32 + (lbase >> 5)) = o;
        }
    }
}

// ============ K4: outpre = y2 @ spikes (16x16x32, B unpacked from bits) ====
// 48d x 128m tile, grid 512 XCD-swizzled: y2 re-read 8x
__global__ __launch_bounds__(256) void attn_out_mfma(
    const unsigned short* __restrict__ y2hi, const unsigned short* __restrict__ y2mi,
    const unsigned short* __restrict__ y2lo,
    const unsigned* __restrict__ bits, float* __restrict__ outpre) {
    __shared__ unsigned short A_hi[48][72], A_mi[48][72], A_lo[48][72];
    const int tid = threadIdx.x;
    const int flat = blockIdx.x;
    const int xcd = flat & 7;
    const int ii = flat >> 3;            // 0..63
    const int tbh = xcd*8 + (ii >> 3);
    const int mtile = ii & 7;
    const int t = tbh >> 4, b = (tbh >> 3) & 1, h = tbh & 7;
    const int tb = t*B_ + b;
    const int w = tid >> 6, lane = tid & 63;
    const int q = lane >> 4, n15 = lane & 15;
    const int mb = mtile*128 + w*32;

    floatx4 acc[3][2];
#pragma unroll
    for (int i = 0; i < 3; i++)
#pragma unroll
        for (int in = 0; in < 2; in++) acc[i][in] = (floatx4){0.f,0.f,0.f,0.f};

    const unsigned* brow0 = bits + ((size_t)(tb*H_ + h)*L_ + mb + n15)*32;
    const unsigned* brow1 = brow0 + 16*32;
    const size_t y2b = ((size_t)tb*C_ + h*48)*L_;

    for (int lt = 0; lt < L_; lt += 64) {
        for (int s = tid; s < 384; s += 256) {
            int r = s >> 3, c = s & 7;
            size_t ro = y2b + (size_t)r*L_ + lt + c*8;
            *(uint4*)&A_hi[r][c*8] = *(const uint4*)(y2hi + ro);
            *(uint4*)&A_mi[r][c*8] = *(const uint4*)(y2mi + ro);
            *(uint4*)&A_lo[r][c*8] = *(const uint4*)(y2lo + ro);
        }
        uint2 bw0 = *(const uint2*)(brow0 + (lt >> 5));
        uint2 bw1 = *(const uint2*)(brow1 + (lt >> 5));
        __syncthreads();
#pragma unroll
        for (int kc = 0; kc < 2; kc++) {
            unsigned word0 = kc ? bw0.y : bw0.x;
            unsigned word1 = kc ? bw1.y : bw1.x;
            unsigned byt0 = (word0 >> (q*8)) & 0xFFu;
            unsigned byt1 = (word1 >> (q*8)) & 0xFFu;
            union { unsigned u[4]; short8 v; } bu0, bu1;
#pragma unroll
            for (int p = 0; p < 4; p++) {
                bu0.u[p] = (((byt0 >> (2*p)) & 1u) ? 0x3F80u : 0u)
                         | (((byt0 >> (2*p+1)) & 1u) ? 0x3F800000u : 0u);
                bu1.u[p] = (((byt1 >> (2*p)) & 1u) ? 0x3F80u : 0u)
                         | (((byt1 >> (2*p+1)) & 1u) ? 0x3F800000u : 0u);
            }
            short8 bf0 = bu0.v, bf1 = bu1.v;
#pragma unroll
            for (int i = 0; i < 3; i++) {
                int ra = i*16 + n15;
                short8 ah = *(short8*)&A_hi[ra][kc*32 + q*8];
                short8 am = *(short8*)&A_mi[ra][kc*32 + q*8];
                short8 al = *(short8*)&A_lo[ra][kc*32 + q*8];
                acc[i][0] = __builtin_amdgcn_mfma_f32_16x16x32_bf16(ah, bf0, acc[i][0], 0,0,0);
                acc[i][0] = __builtin_amdgcn_mfma_f32_16x16x32_bf16(am, bf0, acc[i][0], 0,0,0);
                acc[i][0] = __builtin_amdgcn_mfma_f32_16x16x32_bf16(al, bf0, acc[i][0], 0,0,0);
                acc[i][1] = __builtin_amdgcn_mfma_f32_16x16x32_bf16(ah, bf1, acc[i][1], 0,0,0);
                acc[i][1] = __builtin_amdgcn_mfma_f32_16x16x32_bf16(am, bf1, acc[i][1], 0,0,0);
                acc[i][1] = __builtin_amdgcn_mfma_f32_16x16x32_bf16(al, bf1, acc[i][1], 0,0,0);
            }
        }
        __syncthreads();
    }
#pragma unroll
    for (int i = 0; i < 3; i++)
#pragma unroll
        for (int r = 0; r < 4; r++) {
            int d = i*16 + q*4 + r;
#pragma unroll
            for (int in = 0; in < 2; in++)
                outpre[((size_t)tb*C_ + h*48 + d)*L_ + mb + in*16 + n15] = acc[i][in][r];
        }
}

// ============ K6: out = BN2(proj @ outs) + x (MFMA, 96x64 tile) ============
__global__ __launch_bounds__(256) void gemm2_mfma(
    const unsigned short* __restrict__ whi, const unsigned short* __restrict__ wmi,
    const unsigned short* __restrict__ wlo, const unsigned short* __restrict__ xT,
    const float* __restrict__ g, const float* __restrict__ be,
    const float* __restrict__ mn, const float* __restrict__ vr,
    const float* __restrict__ res, float* __restrict__ out) {
    __shared__ unsigned short A_hi[96][40], A_mi[96][40], A_lo[96][40];
    __shared__ unsigned short B_s[64][40];
    const int tid = threadIdx.x;
    const int tb = blockIdx.y;
    const int mt = blockIdx.x >> 4, lt = blockIdx.x & 15;
    const int l0 = lt * 64;
    const int w = tid >> 6, lane = tid & 63;
    const int q = lane >> 4, n15 = lane & 15;
    const int mw = (w & 1) * 48, lw = (w >> 1) * 32;

    floatx4 acc[3][2];
#pragma unroll
    for (int i = 0; i < 3; i++)
#pragma unroll
        for (int j = 0; j < 2; j++) acc[i][j] = (floatx4){0.f,0.f,0.f,0.f};

    for (int ck = 0; ck < C_; ck += 32) {
#pragma unroll
        for (int p = 0; p < 3; p++) {
            const unsigned short* wp = p == 0 ? whi : p == 1 ? wmi : wlo;
            unsigned short (*ap)[40] = p == 0 ? A_hi : p == 1 ? A_mi : A_lo;
            for (int s = tid; s < 384; s += 256) {
                int r = s >> 2, c = s & 3;
                *(uint4*)&ap[r][c*8] = *(const uint4*)(wp + (size_t)(mt*96 + r)*C_ + ck + c*8);
            }
        }
        {
            int r = tid >> 2, c4 = tid & 3;
            *(uint4*)&B_s[r][c4*8] = *(const uint4*)(xT + ((size_t)tb*L_ + l0 + r)*C_ + ck + c4*8);
        }
        __syncthreads();
        short8 bb[2];
#pragma unroll
        for (int in = 0; in < 2; in++)
            bb[in] = *(short8*)&B_s[lw + in*16 + n15][q*8];
#pragma unroll
        for (int im = 0; im < 3; im++) {
            short8 ah = *(short8*)&A_hi[mw + im*16 + n15][q*8];
            short8 am = *(short8*)&A_mi[mw + im*16 + n15][q*8];
            short8 al = *(short8*)&A_lo[mw + im*16 + n15][q*8];
#pragma unroll
            for (int in = 0; in < 2; in++) {
                acc[im][in] = __builtin_amdgcn_mfma_f32_16x16x32_bf16(ah, bb[in], acc[im][in], 0,0,0);
                acc[im][in] = __builtin_amdgcn_mfma_f32_16x16x32_bf16(am, bb[in], acc[im][in], 0,0,0);
                acc[im][in] = __builtin_amdgcn_mfma_f32_16x16x32_bf16(al, bb[in], acc[im][in], 0,0,0);
            }
        }
        __syncthreads();
    }
#pragma unroll
    for (int im = 0; im < 3; im++)
#pragma unroll
        for (int r = 0; r < 4; r++) {
            int o = mt*96 + mw + im*16 + q*4 + r;
            float inv = g[o] / sqrtf(vr[o] + 1e-5f);
            float sh = be[o] - mn[o]*inv;
#pragma unroll
            for (int in = 0; in < 2; in++) {
                int l = l0 + lw + in*16 + n15;
                size_t idx = ((size_t)tb*C_ + o)*L_ + l;
                out[idx] = acc[im][in][r]*inv + sh + res[idx];
            }
        }
}

extern "C" void kernel_launch(void* const* d_in, const int* in_sizes, int n_in,
                              void* d_out, int out_size, void* d_ws, size_t ws_size,
                              hipStream_t stream) {
    const float* x   = (const float*)d_in[0];
    const float* W_w = (const float*)d_in[1];
    const float* g1  = (const float*)d_in[2];
    const float* b1  = (const float*)d_in[3];
    const float* m1  = (const float*)d_in[4];
    const float* v1  = (const float*)d_in[5];
    const float* pw  = (const float*)d_in[6];
    const float* g2  = (const float*)d_in[7];
    const float* b2  = (const float*)d_in[8];
    const float* m2  = (const float*)d_in[9];
    const float* v2  = (const float*)d_in[10];

    float* ws = (float*)d_ws;
    unsigned short* xsT  = (unsigned short*)ws;               // 1,572,864 f
    unsigned short* y1hi = (unsigned short*)(ws + 1572864);   // 1,572,864 f each
    unsigned short* y1mi = (unsigned short*)(ws + 3145728);
    unsigned short* y1lo = (unsigned short*)(ws + 4718592);
    unsigned short* y2hi = (unsigned short*)(ws + 6291456);
    unsigned short* y2mi = (unsigned short*)(ws + 7864320);
    unsigned short* y2lo = (unsigned short*)(ws + 9437184);
    unsigned*       bits = (unsigned*)(ws + 11010048);        // ends 13,107,200 f
    unsigned short* wspl[3]  = {(unsigned short*)(ws + 13107200),
                                (unsigned short*)(ws + 13254656),
                                (unsigned short*)(ws + 13402112)};
    unsigned short* pwspl[3] = {(unsigned short*)(ws + 13549568),
                                (unsigned short*)(ws + 13623296),
                                (unsigned short*)(ws + 13697024)};  // ends 13,770,752 f = 55.1 MB
    float*          outpre = (float*)(ws + 1572864);          // alias y1hi+y1mi (dead after K3)
    unsigned short* outsT  = (unsigned short*)(ws + 4718592); // alias y1lo (dead after K3)
    float* out = (float*)d_out;

    // 1) [merged] xs spikes scan->bf16 transposed (blocks 0-191) +
    //    fp32->3xbf16 split of BOTH weight tensors (blocks 192-623)
    scan_and_split<<<dim3(624), 256, 0, stream>>>(x, xsT,
                                                  W_w, C2_*C_/4, wspl[0], wspl[1], wspl[2],
                                                  pw,  C_*C_/4, pwspl[0], pwspl[1], pwspl[2]);
    // 2) y = BN1(W @ xs): 96x64 tile, aliased LDS, 1024 blocks XCD-swizzled
    gemm1_mfma<<<dim3(1024), 256, 0, stream>>>(wspl[0], wspl[1], wspl[2], xsT,
                                               g1, b1, m1, v1,
                                               y1hi, y1mi, y1lo, y2hi, y2mi, y2lo);
    // 3) attn spikes: 64l x 128m tile, grid 2048 XCD-swizzled, LDS-free
    attn_spike_mfma<<<dim3(2048), 256, 0, stream>>>(y1hi, y1mi, y1lo, xsT, bits);
    // 4) outpre = y2 @ spikes: 48 x 128 tile, grid 512 XCD-swizzled
    attn_out_mfma<<<dim3(512), 256, 0, stream>>>(y2hi, y2mi, y2lo, bits, outpre);
    // 5) outs spikes -> bf16 transposed
    scan_transpose<<<dim3(16, 6, B_), 256, 0, stream>>>(outpre, outsT);
    // 6) out = BN2(proj @ outs) + x
    gemm2_mfma<<<dim3(64, 8), 256, 0, stream>>>(pwspl[0], pwspl[1], pwspl[2], outsT,
                                                g2, b2, m2, v2, x, out);
}

// Round 7
// 225.753 us; speedup vs baseline: 1.0073x; 1.0073x over previous
//
#include <hip/hip_runtime.h>

#define T_  4
#define B_  2
#define C_  384
#define L_  1024
#define H_  8
#define C2_ 768
#define S_  (B_*C_*L_)

typedef __attribute__((ext_vector_type(8))) short short8;
typedef __attribute__((ext_vector_type(4))) float floatx4;
typedef __attribute__((ext_vector_type(16))) float floatx16;

__device__ __forceinline__ unsigned bf16_rne(float v) {
    unsigned u = __float_as_uint(v);
    u += 0x7FFFu + ((u >> 16) & 1u);
    return u >> 16;
}
__device__ __forceinline__ float bf16_to_f(unsigned h) { return __uint_as_float(h << 16); }
__device__ __forceinline__ void split3(float v, unsigned& hi, unsigned& mi, unsigned& lo) {
    hi = bf16_rne(v);
    float r1 = v - bf16_to_f(hi);
    mi = bf16_rne(r1);
    float r2 = r1 - bf16_to_f(mi);
    lo = bf16_rne(r2);
}

// ==== K1+K0 merged: blocks 0-191 run the xs scan (writing BOTH the [tb][l][c]
// layout for K2 and the fragment-major [tb][h][kc][m][8] layout for K3's B);
// blocks 192-623 split both fp32 weight tensors into 3 bf16 planes.
__global__ __launch_bounds__(256) void scan_and_split(
    const float* __restrict__ src, unsigned short* __restrict__ dstT,
    unsigned short* __restrict__ xsF,
    const float* __restrict__ Wa, int n4a,
    unsigned short* __restrict__ hia, unsigned short* __restrict__ mia,
    unsigned short* __restrict__ loa,
    const float* __restrict__ Wb, int n4b,
    unsigned short* __restrict__ hib, unsigned short* __restrict__ mib,
    unsigned short* __restrict__ lob) {
    __shared__ unsigned short tile[64][72];
    const int tid = threadIdx.x;
    if (blockIdx.x >= 192) {
        int i = (blockIdx.x - 192) * 256 + tid;
        const float* W; unsigned short *hi, *mi, *lo;
        if (i < n4a) { W = Wa; hi = hia; mi = mia; lo = loa; }
        else {
            i -= n4a;
            if (i >= n4b) return;
            W = Wb; hi = hib; mi = mib; lo = lob;
        }
        float4 v = ((const float4*)W)[i];
        float vv[4] = {v.x, v.y, v.z, v.w};
        union { unsigned short us[4]; uint2 u2; } h, m, l;
#pragma unroll
        for (int e = 0; e < 4; e++) {
            unsigned hh, mm, ll; split3(vv[e], hh, mm, ll);
            h.us[e] = (unsigned short)hh; m.us[e] = (unsigned short)mm; l.us[e] = (unsigned short)ll;
        }
        ((uint2*)hi)[i] = h.u2; ((uint2*)mi)[i] = m.u2; ((uint2*)lo)[i] = l.u2;
        return;
    }
    // ---- scan branch: job = blockIdx.x in [0,192) ----
    const int job = blockIdx.x;
    const int l0 = (job & 15) * 64;
    const int c0 = ((job >> 4) % 6) * 64;
    const int b  = job / 96;
    const int row = tid >> 2, seg = tid & 3;
    float mem[16], sp[16];
#pragma unroll
    for (int e = 0; e < 16; e++) { mem[e] = 0.f; sp[e] = 0.f; }
    for (int t = 0; t < T_; t++) {
        const size_t base = ((size_t)((t*B_ + b)*C_ + c0 + row))*L_ + l0 + seg*16;
#pragma unroll
        for (int qq = 0; qq < 4; qq++) {
            float4 v = *(const float4*)(src + base + qq*4);
            float vv[4] = {v.x, v.y, v.z, v.w};
            unsigned bs[4];
#pragma unroll
            for (int s = 0; s < 4; s++) {
                int e = qq*4 + s;
                mem[e] = mem[e]*0.25f*(1.f - sp[e]) + vv[s];
                bool sb = mem[e] > 0.5f;
                sp[e] = sb ? 1.f : 0.f;
                bs[s] = sb ? 0x3F80u : 0u;
            }
            *(unsigned*)&tile[row][seg*16 + qq*4]     = bs[0] | (bs[1] << 16);
            *(unsigned*)&tile[row][seg*16 + qq*4 + 2] = bs[2] | (bs[3] << 16);
        }
        __syncthreads();
        {
            const int lr = tid >> 2, cs = tid & 3;
#pragma unroll
            for (int sub = 0; sub < 2; sub++) {
                unsigned wv[4];
#pragma unroll
                for (int p = 0; p < 4; p++) {
                    unsigned e0 = tile[cs*16 + sub*8 + p*2][lr];
                    unsigned e1 = tile[cs*16 + sub*8 + p*2 + 1][lr];
                    wv[p] = e0 | (e1 << 16);
                }
                uint4 o; o.x = wv[0]; o.y = wv[1]; o.z = wv[2]; o.w = wv[3];
                const int cc = c0 + cs*16 + sub*8;     // multiple of 8
                *(uint4*)(dstT + ((size_t)(t*B_ + b)*L_ + l0 + lr)*C_ + cc) = o;
                // fragment-major copy for K3's B: [tb][h][kc][m][8]
                const int hh = cc / 48, kc = (cc % 48) >> 3;
                *(uint4*)(xsF + ((((size_t)(t*B_ + b)*H_ + hh)*6 + kc)*L_ + l0 + lr)*8) = o;
            }
        }
        __syncthreads();
    }
}

// ============ K5: mem_update scan over T + bf16 spike transpose ============
__global__ __launch_bounds__(256) void scan_transpose(const float* __restrict__ src,
                                                      unsigned short* __restrict__ dstT) {
    __shared__ unsigned short tile[64][72];
    const int tid = threadIdx.x;
    const int l0 = blockIdx.x * 64, c0 = blockIdx.y * 64, b = blockIdx.z;
    const int row = tid >> 2, seg = tid & 3;
    float mem[16], sp[16];
#pragma unroll
    for (int e = 0; e < 16; e++) { mem[e] = 0.f; sp[e] = 0.f; }
    for (int t = 0; t < T_; t++) {
        const size_t base = ((size_t)((t*B_ + b)*C_ + c0 + row))*L_ + l0 + seg*16;
#pragma unroll
        for (int qq = 0; qq < 4; qq++) {
            float4 v = *(const float4*)(src + base + qq*4);
            float vv[4] = {v.x, v.y, v.z, v.w};
            unsigned bs[4];
#pragma unroll
            for (int s = 0; s < 4; s++) {
                int e = qq*4 + s;
                mem[e] = mem[e]*0.25f*(1.f - sp[e]) + vv[s];
                bool sb = mem[e] > 0.5f;
                sp[e] = sb ? 1.f : 0.f;
                bs[s] = sb ? 0x3F80u : 0u;
            }
            *(unsigned*)&tile[row][seg*16 + qq*4]     = bs[0] | (bs[1] << 16);
            *(unsigned*)&tile[row][seg*16 + qq*4 + 2] = bs[2] | (bs[3] << 16);
        }
        __syncthreads();
        {
            const int lr = tid >> 2, cs = tid & 3;
#pragma unroll
            for (int sub = 0; sub < 2; sub++) {
                unsigned wv[4];
#pragma unroll
                for (int p = 0; p < 4; p++) {
                    unsigned e0 = tile[cs*16 + sub*8 + p*2][lr];
                    unsigned e1 = tile[cs*16 + sub*8 + p*2 + 1][lr];
                    wv[p] = e0 | (e1 << 16);
                }
                uint4 o; o.x = wv[0]; o.y = wv[1]; o.z = wv[2]; o.w = wv[3];
                *(uint4*)(dstT + ((size_t)(t*B_ + b)*L_ + l0 + lr)*C_ + c0 + cs*16 + sub*8) = o;
            }
        }
        __syncthreads();
    }
}

// ============ K2: y = BN1(W @ xs) via MFMA, 96m x 64l tile, aliased LDS ====
// y1 is written FRAGMENT-MAJOR: y1f[tb][h][kc=6][l=1024][8elem] so K3's
// A-loads are wave-contiguous. y2 layout unchanged.
__global__ __launch_bounds__(256) void gemm1_mfma(
    const unsigned short* __restrict__ whi, const unsigned short* __restrict__ wmi,
    const unsigned short* __restrict__ wlo, const unsigned short* __restrict__ xsT,
    const float* __restrict__ g, const float* __restrict__ be,
    const float* __restrict__ mn, const float* __restrict__ vr,
    unsigned short* __restrict__ y1hi, unsigned short* __restrict__ y1mi,
    unsigned short* __restrict__ y1lo,
    unsigned short* __restrict__ y2hi, unsigned short* __restrict__ y2mi,
    unsigned short* __restrict__ y2lo) {
    __shared__ unsigned short smem[14080];
    const int tid = threadIdx.x;
    const int flat = blockIdx.x;
    const int tb = flat & 7;
    const int ii = flat >> 3;
    const int mt = ii >> 4, lt = ii & 15;
    const int l0 = lt * 64;
    const int w = tid >> 6, lane = tid & 63;
    const int q = lane >> 4, n15 = lane & 15;
    const int mw = (w & 1) * 48, lw = (w >> 1) * 32;

    floatx4 acc[3][2];
#pragma unroll
    for (int i = 0; i < 3; i++)
#pragma unroll
        for (int j = 0; j < 2; j++) acc[i][j] = (floatx4){0.f,0.f,0.f,0.f};

    for (int ck = 0; ck < C_; ck += 32) {
#pragma unroll
        for (int p = 0; p < 3; p++) {
            const unsigned short* wp = p == 0 ? whi : p == 1 ? wmi : wlo;
            unsigned short* ap = smem + p*3840;
            for (int s = tid; s < 384; s += 256) {
                int r = s >> 2, c = s & 3;
                *(uint4*)&ap[r*40 + c*8] = *(const uint4*)(wp + (size_t)(mt*96 + r)*C_ + ck + c*8);
            }
        }
        {
            int r = tid >> 2, c = tid & 3;
            *(uint4*)&smem[11520 + r*40 + c*8] =
                *(const uint4*)(xsT + ((size_t)tb*L_ + l0 + r)*C_ + ck + c*8);
        }
        __syncthreads();
        short8 bb[2];
#pragma unroll
        for (int in = 0; in < 2; in++)
            bb[in] = *(short8*)&smem[11520 + (lw + in*16 + n15)*40 + q*8];
#pragma unroll
        for (int im = 0; im < 3; im++) {
            short8 ah = *(short8*)&smem[       (mw + im*16 + n15)*40 + q*8];
            short8 am = *(short8*)&smem[3840 + (mw + im*16 + n15)*40 + q*8];
            short8 al = *(short8*)&smem[7680 + (mw + im*16 + n15)*40 + q*8];
#pragma unroll
            for (int in = 0; in < 2; in++) {
                acc[im][in] = __builtin_amdgcn_mfma_f32_16x16x32_bf16(ah, bb[in], acc[im][in], 0,0,0);
                acc[im][in] = __builtin_amdgcn_mfma_f32_16x16x32_bf16(am, bb[in], acc[im][in], 0,0,0);
                acc[im][in] = __builtin_amdgcn_mfma_f32_16x16x32_bf16(al, bb[in], acc[im][in], 0,0,0);
            }
        }
        __syncthreads();
    }

#pragma unroll
    for (int im = 0; im < 3; im++)
#pragma unroll
        for (int r = 0; r < 4; r++) {
            int o = mt*96 + mw + im*16 + q*4 + r;
            float inv = g[o] / sqrtf(vr[o] + 1e-5f);
            float sh = be[o] - mn[o]*inv;
#pragma unroll
            for (int in = 0; in < 2; in++)
                acc[im][in][r] = acc[im][in][r]*inv + sh;
        }
    const bool isY1 = ((w & 1) == 0);
#pragma unroll
    for (int p = 0; p < 3; p++) {
        if (isY1) {
#pragma unroll
            for (int im = 0; im < 3; im++)
#pragma unroll
                for (int in = 0; in < 2; in++) {
                    union { unsigned short us[4]; uint2 u2; } pk;
#pragma unroll
                    for (int r = 0; r < 4; r++) {
                        unsigned hh = bf16_rne(acc[im][in][r]);
                        pk.us[r] = (unsigned short)hh;
                        acc[im][in][r] -= bf16_to_f(hh);
                    }
                    *(uint2*)&smem[(lw + in*16 + n15)*56 + im*16 + q*4] = pk.u2;
                }
        } else {
#pragma unroll
            for (int im = 0; im < 3; im++)
#pragma unroll
                for (int in = 0; in < 2; in++)
#pragma unroll
                    for (int r = 0; r < 4; r++) {
                        unsigned hh = bf16_rne(acc[im][in][r]);
                        smem[3584 + (im*16 + q*4 + r)*72 + lw + in*16 + n15] = (unsigned short)hh;
                        acc[im][in][r] -= bf16_to_f(hh);
                    }
        }
        __syncthreads();
        unsigned short* y1p = p == 0 ? y1hi : p == 1 ? y1mi : y1lo;
        unsigned short* y2p = p == 0 ? y2hi : p == 1 ? y2mi : y2lo;
        // y1 fragment-major store: [tb][h=mt][kc=c8][l0+r1][8]; wave-contiguous
        for (int s = tid; s < 384; s += 256) {
            int c8 = s >> 6, r1 = s & 63;
            *(uint4*)(y1p + ((((size_t)tb*H_ + mt)*6 + c8)*L_ + l0 + r1)*8) =
                *(uint4*)&smem[r1*56 + c8*8];
        }
        for (int s = tid; s < 384; s += 256) {
            int cr = s >> 3, lq = s & 7;
            *(uint4*)(y2p + ((size_t)tb*C_ + mt*48 + cr)*L_ + l0 + lq*8) =
                *(uint4*)&smem[3584 + cr*72 + lq*8];
        }
        __syncthreads();
    }
}

// ============ K3: attn = y1^T @ xr (32x32x16 MFMA, K=48 exact) =============
// 64l x 128m tile, grid 2048 XCD-swizzled. LDS-free AND fully coalesced:
// A from y1f fragment-major layout, B from xsF fragment-major layout — every
// wave load is 2x 512B contiguous segments.
__global__ __launch_bounds__(256, 4) void attn_spike_mfma(
    const unsigned short* __restrict__ y1hi, const unsigned short* __restrict__ y1mi,
    const unsigned short* __restrict__ y1lo, const unsigned short* __restrict__ xsF,
    unsigned* __restrict__ bits) {
    const int tid = threadIdx.x;
    const int flat = blockIdx.x;
    const int xcd = flat & 7;
    const int ii = flat >> 3;            // 0..255
    const int bh = xcd*2 + (ii >> 7);
    const int rr = ii & 127;
    const int b = bh >> 3, h = bh & 7;
    const int lbase = (rr >> 3) * 64;    // 16 l-tiles
    const int mbase = (rr & 7) * 128;    // 8 m-tiles
    const int w = tid >> 6, lane = tid & 63;
    const int l31 = lane & 31, half = lane >> 5;
    const int mrow = mbase + w*32 + l31;

    float mem[2][16];
#pragma unroll
    for (int il = 0; il < 2; il++)
#pragma unroll
        for (int r = 0; r < 16; r++) mem[il][r] = 0.f;

    for (int t = 0; t < T_; t++) {
        const int tb = t*B_ + b;
        const size_t fb = ((size_t)tb*H_ + h)*6*L_*8;   // fragment base (elems)
        const unsigned short* ya_hi = y1hi + fb;
        const unsigned short* ya_mi = y1mi + fb;
        const unsigned short* ya_lo = y1lo + fb;
        const unsigned short* xf    = xsF  + fb;

        // B fragments: kc = ks*2 + half, row mrow -> contiguous per 32-lane half
        short8 bb[3];
#pragma unroll
        for (int ks = 0; ks < 3; ks++)
            bb[ks] = *(const short8*)(xf + ((size_t)(ks*2 + half)*L_ + mrow)*8);

        floatx16 acc[2];
#pragma unroll
        for (int il = 0; il < 2; il++)
#pragma unroll
            for (int r = 0; r < 16; r++) acc[il][r] = 0.f;

#pragma unroll
        for (int ks = 0; ks < 3; ks++) {
#pragma unroll
            for (int il = 0; il < 2; il++) {
                const size_t aoff = ((size_t)(ks*2 + half)*L_ + lbase + il*32 + l31)*8;
                short8 ah = *(const short8*)(ya_hi + aoff);
                short8 am = *(const short8*)(ya_mi + aoff);
                short8 al = *(const short8*)(ya_lo + aoff);
                acc[il] = __builtin_amdgcn_mfma_f32_32x32x16_bf16(ah, bb[ks], acc[il], 0,0,0);
                acc[il] = __builtin_amdgcn_mfma_f32_32x32x16_bf16(am, bb[ks], acc[il], 0,0,0);
                acc[il] = __builtin_amdgcn_mfma_f32_32x32x16_bf16(al, bb[ks], acc[il], 0,0,0);
            }
        }

        unsigned wds[2];
#pragma unroll
        for (int il = 0; il < 2; il++) {
            unsigned word = 0;
#pragma unroll
            for (int r = 0; r < 16; r++) {
                float m = (mem[il][r] > 0.5f ? 0.f : mem[il][r]*0.25f) + acc[il][r];
                mem[il][r] = m;
                int lloc = (r & 3) + 8*(r >> 2) + 4*half;
                word |= (m > 0.5f) ? (1u << lloc) : 0u;
            }
            wds[il] = word;
        }
        unsigned f0 = wds[0] | __shfl_xor(wds[0], 32);
        unsigned f1 = wds[1] | __shfl_xor(wds[1], 32);
        if (half == 0) {
            uint2 o; o.x = f0; o.y = f1;
            *(uint2*)(bits + ((size_t)(tb*H_ + h)*L_ + mrow)*32 + (lbase >> 5)) = o;
        }
    }
}

// ============ K4: outpre = y2 @ spikes (16x16x32, B unpacked from bits) ====
// 48d x 128m tile, grid 512 XCD-swizzled: y2 re-read 8x
__global__ __launch_bounds__(256) void attn_out_mfma(
    const unsigned short* __restrict__ y2hi, const unsigned short* __restrict__ y2mi,
    const unsigned short* __restrict__ y2lo,
    const unsigned* __restrict__ bits, float* __restrict__ outpre) {
    __shared__ unsigned short A_hi[48][72], A_mi[48][72], A_lo[48][72];
    const int tid = threadIdx.x;
    const int flat = blockIdx.x;
    const int xcd = flat & 7;
    const int ii = flat >> 3;            // 0..63
    const int tbh = xcd*8 + (ii >> 3);
    const int mtile = ii & 7;
    const int t = tbh >> 4, b = (tbh >> 3) & 1, h = tbh & 7;
    const int tb = t*B_ + b;
    const int w = tid >> 6, lane = tid & 63;
    const int q = lane >> 4, n15 = lane & 15;
    const int mb = mtile*128 + w*32;

    floatx4 acc[3][2];
#pragma unroll
    for (int i = 0; i < 3; i++)
#pragma unroll
        for (int in = 0; in < 2; in++) acc[i][in] = (floatx4){0.f,0.f,0.f,0.f};

    const unsigned* brow0 = bits + ((size_t)(tb*H_ + h)*L_ + mb + n15)*32;
    const unsigned* brow1 = brow0 + 16*32;
    const size_t y2b = ((size_t)tb*C_ + h*48)*L_;

    for (int lt = 0; lt < L_; lt += 64) {
        for (int s = tid; s < 384; s += 256) {
            int r = s >> 3, c = s & 7;
            size_t ro = y2b + (size_t)r*L_ + lt + c*8;
            *(uint4*)&A_hi[r][c*8] = *(const uint4*)(y2hi + ro);
            *(uint4*)&A_mi[r][c*8] = *(const uint4*)(y2mi + ro);
            *(uint4*)&A_lo[r][c*8] = *(const uint4*)(y2lo + ro);
        }
        uint2 bw0 = *(const uint2*)(brow0 + (lt >> 5));
        uint2 bw1 = *(const uint2*)(brow1 + (lt >> 5));
        __syncthreads();
#pragma unroll
        for (int kc = 0; kc < 2; kc++) {
            unsigned word0 = kc ? bw0.y : bw0.x;
            unsigned word1 = kc ? bw1.y : bw1.x;
            unsigned byt0 = (word0 >> (q*8)) & 0xFFu;
            unsigned byt1 = (word1 >> (q*8)) & 0xFFu;
            union { unsigned u[4]; short8 v; } bu0, bu1;
#pragma unroll
            for (int p = 0; p < 4; p++) {
                bu0.u[p] = (((byt0 >> (2*p)) & 1u) ? 0x3F80u : 0u)
                         | (((byt0 >> (2*p+1)) & 1u) ? 0x3F800000u : 0u);
                bu1.u[p] = (((byt1 >> (2*p)) & 1u) ? 0x3F80u : 0u)
                         | (((byt1 >> (2*p+1)) & 1u) ? 0x3F800000u : 0u);
            }
            short8 bf0 = bu0.v, bf1 = bu1.v;
#pragma unroll
            for (int i = 0; i < 3; i++) {
                int ra = i*16 + n15;
                short8 ah = *(short8*)&A_hi[ra][kc*32 + q*8];
                short8 am = *(short8*)&A_mi[ra][kc*32 + q*8];
                short8 al = *(short8*)&A_lo[ra][kc*32 + q*8];
                acc[i][0] = __builtin_amdgcn_mfma_f32_16x16x32_bf16(ah, bf0, acc[i][0], 0,0,0);
                acc[i][0] = __builtin_amdgcn_mfma_f32_16x16x32_bf16(am, bf0, acc[i][0], 0,0,0);
                acc[i][0] = __builtin_amdgcn_mfma_f32_16x16x32_bf16(al, bf0, acc[i][0], 0,0,0);
                acc[i][1] = __builtin_amdgcn_mfma_f32_16x16x32_bf16(ah, bf1, acc[i][1], 0,0,0);
                acc[i][1] = __builtin_amdgcn_mfma_f32_16x16x32_bf16(am, bf1, acc[i][1], 0,0,0);
                acc[i][1] = __builtin_amdgcn_mfma_f32_16x16x32_bf16(al, bf1, acc[i][1], 0,0,0);
            }
        }
        __syncthreads();
    }
#pragma unroll
    for (int i = 0; i < 3; i++)
#pragma unroll
        for (int r = 0; r < 4; r++) {
            int d = i*16 + q*4 + r;
#pragma unroll
            for (int in = 0; in < 2; in++)
                outpre[((size_t)tb*C_ + h*48 + d)*L_ + mb + in*16 + n15] = acc[i][in][r];
        }
}

// ============ K6: out = BN2(proj @ outs) + x (MFMA, 96x64 tile) ============
__global__ __launch_bounds__(256) void gemm2_mfma(
    const unsigned short* __restrict__ whi, const unsigned short* __restrict__ wmi,
    const unsigned short* __restrict__ wlo, const unsigned short* __restrict__ xT,
    const float* __restrict__ g, const float* __restrict__ be,
    const float* __restrict__ mn, const float* __restrict__ vr,
    const float* __restrict__ res, float* __restrict__ out) {
    __shared__ unsigned short A_hi[96][40], A_mi[96][40], A_lo[96][40];
    __shared__ unsigned short B_s[64][40];
    const int tid = threadIdx.x;
    const int tb = blockIdx.y;
    const int mt = blockIdx.x >> 4, lt = blockIdx.x & 15;
    const int l0 = lt * 64;
    const int w = tid >> 6, lane = tid & 63;
    const int q = lane >> 4, n15 = lane & 15;
    const int mw = (w & 1) * 48, lw = (w >> 1) * 32;

    floatx4 acc[3][2];
#pragma unroll
    for (int i = 0; i < 3; i++)
#pragma unroll
        for (int j = 0; j < 2; j++) acc[i][j] = (floatx4){0.f,0.f,0.f,0.f};

    for (int ck = 0; ck < C_; ck += 32) {
#pragma unroll
        for (int p = 0; p < 3; p++) {
            const unsigned short* wp = p == 0 ? whi : p == 1 ? wmi : wlo;
            unsigned short (*ap)[40] = p == 0 ? A_hi : p == 1 ? A_mi : A_lo;
            for (int s = tid; s < 384; s += 256) {
                int r = s >> 2, c = s & 3;
                *(uint4*)&ap[r][c*8] = *(const uint4*)(wp + (size_t)(mt*96 + r)*C_ + ck + c*8);
            }
        }
        {
            int r = tid >> 2, c4 = tid & 3;
            *(uint4*)&B_s[r][c4*8] = *(const uint4*)(xT + ((size_t)tb*L_ + l0 + r)*C_ + ck + c4*8);
        }
        __syncthreads();
        short8 bb[2];
#pragma unroll
        for (int in = 0; in < 2; in++)
            bb[in] = *(short8*)&B_s[lw + in*16 + n15][q*8];
#pragma unroll
        for (int im = 0; im < 3; im++) {
            short8 ah = *(short8*)&A_hi[mw + im*16 + n15][q*8];
            short8 am = *(short8*)&A_mi[mw + im*16 + n15][q*8];
            short8 al = *(short8*)&A_lo[mw + im*16 + n15][q*8];
#pragma unroll
            for (int in = 0; in < 2; in++) {
                acc[im][in] = __builtin_amdgcn_mfma_f32_16x16x32_bf16(ah, bb[in], acc[im][in], 0,0,0);
                acc[im][in] = __builtin_amdgcn_mfma_f32_16x16x32_bf16(am, bb[in], acc[im][in], 0,0,0);
                acc[im][in] = __builtin_amdgcn_mfma_f32_16x16x32_bf16(al, bb[in], acc[im][in], 0,0,0);
            }
        }
        __syncthreads();
    }
#pragma unroll
    for (int im = 0; im < 3; im++)
#pragma unroll
        for (int r = 0; r < 4; r++) {
            int o = mt*96 + mw + im*16 + q*4 + r;
            float inv = g[o] / sqrtf(vr[o] + 1e-5f);
            float sh = be[o] - mn[o]*inv;
#pragma unroll
            for (int in = 0; in < 2; in++) {
                int l = l0 + lw + in*16 + n15;
                size_t idx = ((size_t)tb*C_ + o)*L_ + l;
                out[idx] = acc[im][in][r]*inv + sh + res[idx];
            }
        }
}

extern "C" void kernel_launch(void* const* d_in, const int* in_sizes, int n_in,
                              void* d_out, int out_size, void* d_ws, size_t ws_size,
                              hipStream_t stream) {
    const float* x   = (const float*)d_in[0];
    const float* W_w = (const float*)d_in[1];
    const float* g1  = (const float*)d_in[2];
    const float* b1  = (const float*)d_in[3];
    const float* m1  = (const float*)d_in[4];
    const float* v1  = (const float*)d_in[5];
    const float* pw  = (const float*)d_in[6];
    const float* g2  = (const float*)d_in[7];
    const float* b2  = (const float*)d_in[8];
    const float* m2  = (const float*)d_in[9];
    const float* v2  = (const float*)d_in[10];

    float* ws = (float*)d_ws;
    unsigned short* xsT  = (unsigned short*)ws;               // 1,572,864 f
    unsigned short* y1hi = (unsigned short*)(ws + 1572864);   // 1,572,864 f each
    unsigned short* y1mi = (unsigned short*)(ws + 3145728);
    unsigned short* y1lo = (unsigned short*)(ws + 4718592);
    unsigned short* y2hi = (unsigned short*)(ws + 6291456);
    unsigned short* y2mi = (unsigned short*)(ws + 7864320);
    unsigned short* y2lo = (unsigned short*)(ws + 9437184);
    unsigned*       bits = (unsigned*)(ws + 11010048);        // ends 13,107,200 f
    unsigned short* wspl[3]  = {(unsigned short*)(ws + 13107200),
                                (unsigned short*)(ws + 13254656),
                                (unsigned short*)(ws + 13402112)};
    unsigned short* pwspl[3] = {(unsigned short*)(ws + 13549568),
                                (unsigned short*)(ws + 13623296),
                                (unsigned short*)(ws + 13697024)};  // ends 13,770,752 f
    unsigned short* xsF  = (unsigned short*)(ws + 13770752);  // fragment-major xs, 1,572,864 f
    float*          outpre = (float*)(ws + 1572864);          // alias y1hi+y1mi (dead after K3)
    unsigned short* outsT  = (unsigned short*)(ws + 4718592); // alias y1lo (dead after K3)
    float* out = (float*)d_out;

    // 1) [merged] xs spikes scan (both layouts) + weight split
    scan_and_split<<<dim3(624), 256, 0, stream>>>(x, xsT, xsF,
                                                  W_w, C2_*C_/4, wspl[0], wspl[1], wspl[2],
                                                  pw,  C_*C_/4, pwspl[0], pwspl[1], pwspl[2]);
    // 2) y = BN1(W @ xs): 96x64 tile; y1 stored fragment-major
    gemm1_mfma<<<dim3(1024), 256, 0, stream>>>(wspl[0], wspl[1], wspl[2], xsT,
                                               g1, b1, m1, v1,
                                               y1hi, y1mi, y1lo, y2hi, y2mi, y2lo);
    // 3) attn spikes: LDS-free, fully coalesced fragment loads
    attn_spike_mfma<<<dim3(2048), 256, 0, stream>>>(y1hi, y1mi, y1lo, xsF, bits);
    // 4) outpre = y2 @ spikes: 48 x 128 tile
    attn_out_mfma<<<dim3(512), 256, 0, stream>>>(y2hi, y2mi, y2lo, bits, outpre);
    // 5) outs spikes -> bf16 transposed
    scan_transpose<<<dim3(16, 6, B_), 256, 0, stream>>>(outpre, outsT);
    // 6) out = BN2(proj @ outs) + x
    gemm2_mfma<<<dim3(64, 8), 256, 0, stream>>>(pwspl[0], pwspl[1], pwspl[2], outsT,
                                                g2, b2, m2, v2, x, out);
}

// Round 8
// 212.299 us; speedup vs baseline: 1.0712x; 1.0634x over previous
//
#include <hip/hip_runtime.h>

#define T_  4
#define B_  2
#define C_  384
#define L_  1024
#define H_  8
#define C2_ 768

typedef __attribute__((ext_vector_type(8))) short short8;
typedef __attribute__((ext_vector_type(4))) float floatx4;
typedef __attribute__((ext_vector_type(16))) float floatx16;

__device__ __forceinline__ unsigned bf16_rne(float v) {
    unsigned u = __float_as_uint(v);
    u += 0x7FFFu + ((u >> 16) & 1u);
    return u >> 16;
}
__device__ __forceinline__ float bf16_to_f(unsigned h) { return __uint_as_float(h << 16); }
__device__ __forceinline__ void split3(float v, unsigned& hi, unsigned& mi, unsigned& lo) {
    hi = bf16_rne(v);
    float r1 = v - bf16_to_f(hi);
    mi = bf16_rne(r1);
    float r2 = r1 - bf16_to_f(mi);
    lo = bf16_rne(r2);
}

// ==== K1+K0: blocks 0-383 run the xs scan (64l x 32c tiles, prefetched);
// blocks 384-815 split both fp32 weight tensors into 3 bf16 planes.
__global__ __launch_bounds__(256) void scan_and_split(
    const float* __restrict__ src, unsigned short* __restrict__ dstT,
    unsigned short* __restrict__ xsF,
    const float* __restrict__ Wa, int n4a,
    unsigned short* __restrict__ hia, unsigned short* __restrict__ mia,
    unsigned short* __restrict__ loa,
    const float* __restrict__ Wb, int n4b,
    unsigned short* __restrict__ hib, unsigned short* __restrict__ mib,
    unsigned short* __restrict__ lob) {
    __shared__ unsigned short tile[32][72];
    const int tid = threadIdx.x;
    if (blockIdx.x >= 384) {
        int i = (blockIdx.x - 384) * 256 + tid;
        const float* W; unsigned short *hi, *mi, *lo;
        if (i < n4a) { W = Wa; hi = hia; mi = mia; lo = loa; }
        else {
            i -= n4a;
            if (i >= n4b) return;
            W = Wb; hi = hib; mi = mib; lo = lob;
        }
        float4 v = ((const float4*)W)[i];
        float vv[4] = {v.x, v.y, v.z, v.w};
        union { unsigned short us[4]; uint2 u2; } h, m, l;
#pragma unroll
        for (int e = 0; e < 4; e++) {
            unsigned hh, mm, ll; split3(vv[e], hh, mm, ll);
            h.us[e] = (unsigned short)hh; m.us[e] = (unsigned short)mm; l.us[e] = (unsigned short)ll;
        }
        ((uint2*)hi)[i] = h.u2; ((uint2*)mi)[i] = m.u2; ((uint2*)lo)[i] = l.u2;
        return;
    }
    // ---- scan branch: job 0..383 = l0(16) x c0(12) x b(2) ----
    const int job = blockIdx.x;
    const int l0 = (job & 15) * 64;
    const int c0 = ((job >> 4) % 12) * 32;
    const int b  = job / 192;
    const int row = tid >> 3, seg = tid & 7;     // 32 c-rows x 8 l-segs
    float mem[8], sp[8];
#pragma unroll
    for (int e = 0; e < 8; e++) { mem[e] = 0.f; sp[e] = 0.f; }
    const size_t base0 = ((size_t)(b*C_ + c0 + row))*L_ + l0 + seg*8;
    float4 nx0 = *(const float4*)(src + base0);
    float4 nx1 = *(const float4*)(src + base0 + 4);
    for (int t = 0; t < T_; t++) {
        float4 v0 = nx0, v1 = nx1;
        if (t < 3) {
            const size_t nb = ((size_t)(((t+1)*B_ + b)*C_ + c0 + row))*L_ + l0 + seg*8;
            nx0 = *(const float4*)(src + nb);
            nx1 = *(const float4*)(src + nb + 4);
        }
        float vv[8] = {v0.x,v0.y,v0.z,v0.w,v1.x,v1.y,v1.z,v1.w};
        unsigned bs[8];
#pragma unroll
        for (int e = 0; e < 8; e++) {
            mem[e] = mem[e]*0.25f*(1.f - sp[e]) + vv[e];
            bool sb = mem[e] > 0.5f;
            sp[e] = sb ? 1.f : 0.f;
            bs[e] = sb ? 0x3F80u : 0u;
        }
#pragma unroll
        for (int p2 = 0; p2 < 4; p2++)
            *(unsigned*)&tile[row][seg*8 + p2*2] = bs[p2*2] | (bs[p2*2+1] << 16);
        __syncthreads();
        {
            const int lr = tid >> 2, cs = tid & 3;   // 64 l-rows x 4 c-chunks
            unsigned wv[4];
#pragma unroll
            for (int p = 0; p < 4; p++) {
                unsigned e0 = tile[cs*8 + p*2][lr];
                unsigned e1 = tile[cs*8 + p*2 + 1][lr];
                wv[p] = e0 | (e1 << 16);
            }
            uint4 o; o.x = wv[0]; o.y = wv[1]; o.z = wv[2]; o.w = wv[3];
            const int cc = c0 + cs*8;
            *(uint4*)(dstT + ((size_t)(t*B_ + b)*L_ + l0 + lr)*C_ + cc) = o;
            const int hh = cc / 48, kc = (cc % 48) >> 3;
            *(uint4*)(xsF + ((((size_t)(t*B_ + b)*H_ + hh)*6 + kc)*L_ + l0 + lr)*8) = o;
        }
        __syncthreads();
    }
}

// ============ K5: scan over T of (outpre + outpre2) + bf16 transpose =======
// 64l x 32c tiles -> 384 blocks; next-t loads prefetched.
__global__ __launch_bounds__(256) void scan_transpose2(
    const float* __restrict__ srcA, const float* __restrict__ srcB,
    unsigned short* __restrict__ dstT) {
    __shared__ unsigned short tile[32][72];
    const int tid = threadIdx.x;
    const int job = blockIdx.x;
    const int l0 = (job & 15) * 64;
    const int c0 = ((job >> 4) % 12) * 32;
    const int b  = job / 192;
    const int row = tid >> 3, seg = tid & 7;
    float mem[8], sp[8];
#pragma unroll
    for (int e = 0; e < 8; e++) { mem[e] = 0.f; sp[e] = 0.f; }
    const size_t base0 = ((size_t)(b*C_ + c0 + row))*L_ + l0 + seg*8;
    float4 na0 = *(const float4*)(srcA + base0);
    float4 na1 = *(const float4*)(srcA + base0 + 4);
    float4 nb0 = *(const float4*)(srcB + base0);
    float4 nb1 = *(const float4*)(srcB + base0 + 4);
    for (int t = 0; t < T_; t++) {
        float4 a0 = na0, a1 = na1, b0 = nb0, b1 = nb1;
        if (t < 3) {
            const size_t nb = ((size_t)(((t+1)*B_ + b)*C_ + c0 + row))*L_ + l0 + seg*8;
            na0 = *(const float4*)(srcA + nb);
            na1 = *(const float4*)(srcA + nb + 4);
            nb0 = *(const float4*)(srcB + nb);
            nb1 = *(const float4*)(srcB + nb + 4);
        }
        float vv[8] = {a0.x+b0.x, a0.y+b0.y, a0.z+b0.z, a0.w+b0.w,
                       a1.x+b1.x, a1.y+b1.y, a1.z+b1.z, a1.w+b1.w};
        unsigned bs[8];
#pragma unroll
        for (int e = 0; e < 8; e++) {
            mem[e] = mem[e]*0.25f*(1.f - sp[e]) + vv[e];
            bool sb = mem[e] > 0.5f;
            sp[e] = sb ? 1.f : 0.f;
            bs[e] = sb ? 0x3F80u : 0u;
        }
#pragma unroll
        for (int p2 = 0; p2 < 4; p2++)
            *(unsigned*)&tile[row][seg*8 + p2*2] = bs[p2*2] | (bs[p2*2+1] << 16);
        __syncthreads();
        {
            const int lr = tid >> 2, cs = tid & 3;
            unsigned wv[4];
#pragma unroll
            for (int p = 0; p < 4; p++) {
                unsigned e0 = tile[cs*8 + p*2][lr];
                unsigned e1 = tile[cs*8 + p*2 + 1][lr];
                wv[p] = e0 | (e1 << 16);
            }
            uint4 o; o.x = wv[0]; o.y = wv[1]; o.z = wv[2]; o.w = wv[3];
            *(uint4*)(dstT + ((size_t)(t*B_ + b)*L_ + l0 + lr)*C_ + c0 + cs*8) = o;
        }
        __syncthreads();
    }
}

// ============ K2: y = BN1(W @ xs) via MFMA, 96m x 64l tile, aliased LDS ====
__global__ __launch_bounds__(256) void gemm1_mfma(
    const unsigned short* __restrict__ whi, const unsigned short* __restrict__ wmi,
    const unsigned short* __restrict__ wlo, const unsigned short* __restrict__ xsT,
    const float* __restrict__ g, const float* __restrict__ be,
    const float* __restrict__ mn, const float* __restrict__ vr,
    unsigned short* __restrict__ y1hi, unsigned short* __restrict__ y1mi,
    unsigned short* __restrict__ y1lo,
    unsigned short* __restrict__ y2hi, unsigned short* __restrict__ y2mi,
    unsigned short* __restrict__ y2lo) {
    __shared__ unsigned short smem[14080];
    const int tid = threadIdx.x;
    const int flat = blockIdx.x;
    const int tb = flat & 7;
    const int ii = flat >> 3;
    const int mt = ii >> 4, lt = ii & 15;
    const int l0 = lt * 64;
    const int w = tid >> 6, lane = tid & 63;
    const int q = lane >> 4, n15 = lane & 15;
    const int mw = (w & 1) * 48, lw = (w >> 1) * 32;

    floatx4 acc[3][2];
#pragma unroll
    for (int i = 0; i < 3; i++)
#pragma unroll
        for (int j = 0; j < 2; j++) acc[i][j] = (floatx4){0.f,0.f,0.f,0.f};

    for (int ck = 0; ck < C_; ck += 32) {
#pragma unroll
        for (int p = 0; p < 3; p++) {
            const unsigned short* wp = p == 0 ? whi : p == 1 ? wmi : wlo;
            unsigned short* ap = smem + p*3840;
            for (int s = tid; s < 384; s += 256) {
                int r = s >> 2, c = s & 3;
                *(uint4*)&ap[r*40 + c*8] = *(const uint4*)(wp + (size_t)(mt*96 + r)*C_ + ck + c*8);
            }
        }
        {
            int r = tid >> 2, c = tid & 3;
            *(uint4*)&smem[11520 + r*40 + c*8] =
                *(const uint4*)(xsT + ((size_t)tb*L_ + l0 + r)*C_ + ck + c*8);
        }
        __syncthreads();
        short8 bb[2];
#pragma unroll
        for (int in = 0; in < 2; in++)
            bb[in] = *(short8*)&smem[11520 + (lw + in*16 + n15)*40 + q*8];
#pragma unroll
        for (int im = 0; im < 3; im++) {
            short8 ah = *(short8*)&smem[       (mw + im*16 + n15)*40 + q*8];
            short8 am = *(short8*)&smem[3840 + (mw + im*16 + n15)*40 + q*8];
            short8 al = *(short8*)&smem[7680 + (mw + im*16 + n15)*40 + q*8];
#pragma unroll
            for (int in = 0; in < 2; in++) {
                acc[im][in] = __builtin_amdgcn_mfma_f32_16x16x32_bf16(ah, bb[in], acc[im][in], 0,0,0);
                acc[im][in] = __builtin_amdgcn_mfma_f32_16x16x32_bf16(am, bb[in], acc[im][in], 0,0,0);
                acc[im][in] = __builtin_amdgcn_mfma_f32_16x16x32_bf16(al, bb[in], acc[im][in], 0,0,0);
            }
        }
        __syncthreads();
    }

#pragma unroll
    for (int im = 0; im < 3; im++)
#pragma unroll
        for (int r = 0; r < 4; r++) {
            int o = mt*96 + mw + im*16 + q*4 + r;
            float inv = g[o] / sqrtf(vr[o] + 1e-5f);
            float sh = be[o] - mn[o]*inv;
#pragma unroll
            for (int in = 0; in < 2; in++)
                acc[im][in][r] = acc[im][in][r]*inv + sh;
        }
    const bool isY1 = ((w & 1) == 0);
#pragma unroll
    for (int p = 0; p < 3; p++) {
        if (isY1) {
#pragma unroll
            for (int im = 0; im < 3; im++)
#pragma unroll
                for (int in = 0; in < 2; in++) {
                    union { unsigned short us[4]; uint2 u2; } pk;
#pragma unroll
                    for (int r = 0; r < 4; r++) {
                        unsigned hh = bf16_rne(acc[im][in][r]);
                        pk.us[r] = (unsigned short)hh;
                        acc[im][in][r] -= bf16_to_f(hh);
                    }
                    *(uint2*)&smem[(lw + in*16 + n15)*56 + im*16 + q*4] = pk.u2;
                }
        } else {
#pragma unroll
            for (int im = 0; im < 3; im++)
#pragma unroll
                for (int in = 0; in < 2; in++)
#pragma unroll
                    for (int r = 0; r < 4; r++) {
                        unsigned hh = bf16_rne(acc[im][in][r]);
                        smem[3584 + (im*16 + q*4 + r)*72 + lw + in*16 + n15] = (unsigned short)hh;
                        acc[im][in][r] -= bf16_to_f(hh);
                    }
        }
        __syncthreads();
        unsigned short* y1p = p == 0 ? y1hi : p == 1 ? y1mi : y1lo;
        unsigned short* y2p = p == 0 ? y2hi : p == 1 ? y2mi : y2lo;
        for (int s = tid; s < 384; s += 256) {
            int c8 = s >> 6, r1 = s & 63;
            *(uint4*)(y1p + ((((size_t)tb*H_ + mt)*6 + c8)*L_ + l0 + r1)*8) =
                *(uint4*)&smem[r1*56 + c8*8];
        }
        for (int s = tid; s < 384; s += 256) {
            int cr = s >> 3, lq = s & 7;
            *(uint4*)(y2p + ((size_t)tb*C_ + mt*48 + cr)*L_ + l0 + lq*8) =
                *(uint4*)&smem[3584 + cr*72 + lq*8];
        }
        __syncthreads();
    }
}

// ============ K3: attn = y1^T @ xr, LDS-free, coalesced fragment loads =====
// bits stored TRANSPOSED: uint2{f0,f1} at [tbh][l/64][m] -> 256B-contiguous
// writes here, 128B-contiguous reads in K4.
__global__ __launch_bounds__(256, 4) void attn_spike_mfma(
    const unsigned short* __restrict__ y1hi, const unsigned short* __restrict__ y1mi,
    const unsigned short* __restrict__ y1lo, const unsigned short* __restrict__ xsF,
    unsigned* __restrict__ bits) {
    const int tid = threadIdx.x;
    const int flat = blockIdx.x;
    const int xcd = flat & 7;
    const int ii = flat >> 3;            // 0..255
    const int bh = xcd*2 + (ii >> 7);
    const int rr = ii & 127;
    const int b = bh >> 3, h = bh & 7;
    const int lbase = (rr >> 3) * 64;
    const int mbase = (rr & 7) * 128;
    const int w = tid >> 6, lane = tid & 63;
    const int l31 = lane & 31, half = lane >> 5;
    const int mrow = mbase + w*32 + l31;

    float mem[2][16];
#pragma unroll
    for (int il = 0; il < 2; il++)
#pragma unroll
        for (int r = 0; r < 16; r++) mem[il][r] = 0.f;

    for (int t = 0; t < T_; t++) {
        const int tb = t*B_ + b;
        const size_t fb = ((size_t)tb*H_ + h)*6*L_*8;
        const unsigned short* ya_hi = y1hi + fb;
        const unsigned short* ya_mi = y1mi + fb;
        const unsigned short* ya_lo = y1lo + fb;
        const unsigned short* xf    = xsF  + fb;

        short8 bb[3];
#pragma unroll
        for (int ks = 0; ks < 3; ks++)
            bb[ks] = *(const short8*)(xf + ((size_t)(ks*2 + half)*L_ + mrow)*8);

        floatx16 acc[2];
#pragma unroll
        for (int il = 0; il < 2; il++)
#pragma unroll
            for (int r = 0; r < 16; r++) acc[il][r] = 0.f;

#pragma unroll
        for (int ks = 0; ks < 3; ks++) {
#pragma unroll
            for (int il = 0; il < 2; il++) {
                const size_t aoff = ((size_t)(ks*2 + half)*L_ + lbase + il*32 + l31)*8;
                short8 ah = *(const short8*)(ya_hi + aoff);
                short8 am = *(const short8*)(ya_mi + aoff);
                short8 al = *(const short8*)(ya_lo + aoff);
                acc[il] = __builtin_amdgcn_mfma_f32_32x32x16_bf16(ah, bb[ks], acc[il], 0,0,0);
                acc[il] = __builtin_amdgcn_mfma_f32_32x32x16_bf16(am, bb[ks], acc[il], 0,0,0);
                acc[il] = __builtin_amdgcn_mfma_f32_32x32x16_bf16(al, bb[ks], acc[il], 0,0,0);
            }
        }

        unsigned wds[2];
#pragma unroll
        for (int il = 0; il < 2; il++) {
            unsigned word = 0;
#pragma unroll
            for (int r = 0; r < 16; r++) {
                float m = (mem[il][r] > 0.5f ? 0.f : mem[il][r]*0.25f) + acc[il][r];
                mem[il][r] = m;
                int lloc = (r & 3) + 8*(r >> 2) + 4*half;
                word |= (m > 0.5f) ? (1u << lloc) : 0u;
            }
            wds[il] = word;
        }
        unsigned f0 = wds[0] | __shfl_xor(wds[0], 32);
        unsigned f1 = wds[1] | __shfl_xor(wds[1], 32);
        if (half == 0) {
            uint2 o; o.x = f0; o.y = f1;
            ((uint2*)bits)[((size_t)(tb*H_ + h)*16 + (lbase >> 6))*1024 + mrow] = o;
        }
    }
}

// ============ K4: outpre = y2 @ spikes, split-K over l (2 halves) ==========
// grid 1024 XCD-swizzled (4/CU); register-prefetched staging; coalesced bits.
__global__ __launch_bounds__(256) void attn_out_mfma(
    const unsigned short* __restrict__ y2hi, const unsigned short* __restrict__ y2mi,
    const unsigned short* __restrict__ y2lo,
    const unsigned* __restrict__ bits,
    float* __restrict__ outpre, float* __restrict__ outpre2) {
    __shared__ unsigned short A_hi[48][72], A_mi[48][72], A_lo[48][72];
    const int tid = threadIdx.x;
    const int flat = blockIdx.x;
    const int xcd = flat & 7;
    const int ii = flat >> 3;            // 0..127
    const int tbh = xcd*8 + (ii >> 4);
    const int mtile = (ii >> 1) & 7;
    const int ls = ii & 1;
    const int t = tbh >> 4, b = (tbh >> 3) & 1, h = tbh & 7;
    const int tb = t*B_ + b;
    const int w = tid >> 6, lane = tid & 63;
    const int q = lane >> 4, n15 = lane & 15;
    const int mb = mtile*128 + w*32;
    const int lt0 = ls * 512;

    floatx4 acc[3][2];
#pragma unroll
    for (int i = 0; i < 3; i++)
#pragma unroll
        for (int in = 0; in < 2; in++) acc[i][in] = (floatx4){0.f,0.f,0.f,0.f};

    const uint2* bvec = (const uint2*)bits;
    const size_t bbase = ((size_t)(tb*H_ + h)*16)*1024 + mb + n15;
    const size_t y2b = ((size_t)tb*C_ + h*48)*L_;

    // register prefetch staging: s0 = tid (all), s1 = tid+256 (tid<128)
    const int r0 = tid >> 3, c0i = tid & 7;
    const int r1 = (tid + 256) >> 3, c1i = tid & 7;   // (tid+256)&7 == tid&7
    uint4 rh0, rm0, rl0, rh1, rm1, rl1;
    {
        size_t ro = y2b + (size_t)r0*L_ + lt0 + c0i*8;
        rh0 = *(const uint4*)(y2hi + ro); rm0 = *(const uint4*)(y2mi + ro); rl0 = *(const uint4*)(y2lo + ro);
        if (tid < 128) {
            size_t ro1 = y2b + (size_t)r1*L_ + lt0 + c1i*8;
            rh1 = *(const uint4*)(y2hi + ro1); rm1 = *(const uint4*)(y2mi + ro1); rl1 = *(const uint4*)(y2lo + ro1);
        }
    }

    for (int it = 0; it < 8; it++) {
        const int lt = lt0 + it*64;
        // regs -> LDS
        *(uint4*)&A_hi[r0][c0i*8] = rh0; *(uint4*)&A_mi[r0][c0i*8] = rm0; *(uint4*)&A_lo[r0][c0i*8] = rl0;
        if (tid < 128) {
            *(uint4*)&A_hi[r1][c1i*8] = rh1; *(uint4*)&A_mi[r1][c1i*8] = rm1; *(uint4*)&A_lo[r1][c1i*8] = rl1;
        }
        uint2 bw0 = bvec[bbase + (size_t)(lt >> 6)*1024];
        uint2 bw1 = bvec[bbase + (size_t)(lt >> 6)*1024 + 16];
        __syncthreads();
        // prefetch next lt under compute
        if (it < 7) {
            size_t ro = y2b + (size_t)r0*L_ + (lt + 64) + c0i*8;
            rh0 = *(const uint4*)(y2hi + ro); rm0 = *(const uint4*)(y2mi + ro); rl0 = *(const uint4*)(y2lo + ro);
            if (tid < 128) {
                size_t ro1 = y2b + (size_t)r1*L_ + (lt + 64) + c1i*8;
                rh1 = *(const uint4*)(y2hi + ro1); rm1 = *(const uint4*)(y2mi + ro1); rl1 = *(const uint4*)(y2lo + ro1);
            }
        }
#pragma unroll
        for (int kc = 0; kc < 2; kc++) {
            unsigned word0 = kc ? bw0.y : bw0.x;
            unsigned word1 = kc ? bw1.y : bw1.x;
            unsigned byt0 = (word0 >> (q*8)) & 0xFFu;
            unsigned byt1 = (word1 >> (q*8)) & 0xFFu;
            union { unsigned u[4]; short8 v; } bu0, bu1;
#pragma unroll
            for (int p = 0; p < 4; p++) {
                bu0.u[p] = (((byt0 >> (2*p)) & 1u) ? 0x3F80u : 0u)
                         | (((byt0 >> (2*p+1)) & 1u) ? 0x3F800000u : 0u);
                bu1.u[p] = (((byt1 >> (2*p)) & 1u) ? 0x3F80u : 0u)
                         | (((byt1 >> (2*p+1)) & 1u) ? 0x3F800000u : 0u);
            }
            short8 bf0 = bu0.v, bf1 = bu1.v;
#pragma unroll
            for (int i = 0; i < 3; i++) {
                int ra = i*16 + n15;
                short8 ah = *(short8*)&A_hi[ra][kc*32 + q*8];
                short8 am = *(short8*)&A_mi[ra][kc*32 + q*8];
                short8 al = *(short8*)&A_lo[ra][kc*32 + q*8];
                acc[i][0] = __builtin_amdgcn_mfma_f32_16x16x32_bf16(ah, bf0, acc[i][0], 0,0,0);
                acc[i][0] = __builtin_amdgcn_mfma_f32_16x16x32_bf16(am, bf0, acc[i][0], 0,0,0);
                acc[i][0] = __builtin_amdgcn_mfma_f32_16x16x32_bf16(al, bf0, acc[i][0], 0,0,0);
                acc[i][1] = __builtin_amdgcn_mfma_f32_16x16x32_bf16(ah, bf1, acc[i][1], 0,0,0);
                acc[i][1] = __builtin_amdgcn_mfma_f32_16x16x32_bf16(am, bf1, acc[i][1], 0,0,0);
                acc[i][1] = __builtin_amdgcn_mfma_f32_16x16x32_bf16(al, bf1, acc[i][1], 0,0,0);
            }
        }
        __syncthreads();
    }
    float* outP = ls ? outpre2 : outpre;
#pragma unroll
    for (int i = 0; i < 3; i++)
#pragma unroll
        for (int r = 0; r < 4; r++) {
            int d = i*16 + q*4 + r;
#pragma unroll
            for (int in = 0; in < 2; in++)
                outP[((size_t)tb*C_ + h*48 + d)*L_ + mb + in*16 + n15] = acc[i][in][r];
        }
}

// ============ K6: out = BN2(proj @ outs) + x (MFMA, 96x64 tile) ============
__global__ __launch_bounds__(256) void gemm2_mfma(
    const unsigned short* __restrict__ whi, const unsigned short* __restrict__ wmi,
    const unsigned short* __restrict__ wlo, const unsigned short* __restrict__ xT,
    const float* __restrict__ g, const float* __restrict__ be,
    const float* __restrict__ mn, const float* __restrict__ vr,
    const float* __restrict__ res, float* __restrict__ out) {
    __shared__ unsigned short A_hi[96][40], A_mi[96][40], A_lo[96][40];
    __shared__ unsigned short B_s[64][40];
    const int tid = threadIdx.x;
    const int tb = blockIdx.y;
    const int mt = blockIdx.x >> 4, lt = blockIdx.x & 15;
    const int l0 = lt * 64;
    const int w = tid >> 6, lane = tid & 63;
    const int q = lane >> 4, n15 = lane & 15;
    const int mw = (w & 1) * 48, lw = (w >> 1) * 32;

    floatx4 acc[3][2];
#pragma unroll
    for (int i = 0; i < 3; i++)
#pragma unroll
        for (int j = 0; j < 2; j++) acc[i][j] = (floatx4){0.f,0.f,0.f,0.f};

    for (int ck = 0; ck < C_; ck += 32) {
#pragma unroll
        for (int p = 0; p < 3; p++) {
            const unsigned short* wp = p == 0 ? whi : p == 1 ? wmi : wlo;
            unsigned short (*ap)[40] = p == 0 ? A_hi : p == 1 ? A_mi : A_lo;
            for (int s = tid; s < 384; s += 256) {
                int r = s >> 2, c = s & 3;
                *(uint4*)&ap[r][c*8] = *(const uint4*)(wp + (size_t)(mt*96 + r)*C_ + ck + c*8);
            }
        }
        {
            int r = tid >> 2, c4 = tid & 3;
            *(uint4*)&B_s[r][c4*8] = *(const uint4*)(xT + ((size_t)tb*L_ + l0 + r)*C_ + ck + c4*8);
        }
        __syncthreads();
        short8 bb[2];
#pragma unroll
        for (int in = 0; in < 2; in++)
            bb[in] = *(short8*)&B_s[lw + in*16 + n15][q*8];
#pragma unroll
        for (int im = 0; im < 3; im++) {
            short8 ah = *(short8*)&A_hi[mw + im*16 + n15][q*8];
            short8 am = *(short8*)&A_mi[mw + im*16 + n15][q*8];
            short8 al = *(short8*)&A_lo[mw + im*16 + n15][q*8];
#pragma unroll
            for (int in = 0; in < 2; in++) {
                acc[im][in] = __builtin_amdgcn_mfma_f32_16x16x32_bf16(ah, bb[in], acc[im][in], 0,0,0);
                acc[im][in] = __builtin_amdgcn_mfma_f32_16x16x32_bf16(am, bb[in], acc[im][in], 0,0,0);
                acc[im][in] = __builtin_amdgcn_mfma_f32_16x16x32_bf16(al, bb[in], acc[im][in], 0,0,0);
            }
        }
        __syncthreads();
    }
#pragma unroll
    for (int im = 0; im < 3; im++)
#pragma unroll
        for (int r = 0; r < 4; r++) {
            int o = mt*96 + mw + im*16 + q*4 + r;
            float inv = g[o] / sqrtf(vr[o] + 1e-5f);
            float sh = be[o] - mn[o]*inv;
#pragma unroll
            for (int in = 0; in < 2; in++) {
                int l = l0 + lw + in*16 + n15;
                size_t idx = ((size_t)tb*C_ + o)*L_ + l;
                out[idx] = acc[im][in][r]*inv + sh + res[idx];
            }
        }
}

extern "C" void kernel_launch(void* const* d_in, const int* in_sizes, int n_in,
                              void* d_out, int out_size, void* d_ws, size_t ws_size,
                              hipStream_t stream) {
    const float* x   = (const float*)d_in[0];
    const float* W_w = (const float*)d_in[1];
    const float* g1  = (const float*)d_in[2];
    const float* b1  = (const float*)d_in[3];
    const float* m1  = (const float*)d_in[4];
    const float* v1  = (const float*)d_in[5];
    const float* pw  = (const float*)d_in[6];
    const float* g2  = (const float*)d_in[7];
    const float* b2  = (const float*)d_in[8];
    const float* m2  = (const float*)d_in[9];
    const float* v2  = (const float*)d_in[10];

    float* ws = (float*)d_ws;
    unsigned short* xsT  = (unsigned short*)ws;               // 1,572,864 sh
    unsigned short* y1hi = (unsigned short*)(ws + 1572864);
    unsigned short* y1mi = (unsigned short*)(ws + 3145728);
    unsigned short* y1lo = (unsigned short*)(ws + 4718592);
    unsigned short* y2hi = (unsigned short*)(ws + 6291456);
    unsigned short* y2mi = (unsigned short*)(ws + 7864320);
    unsigned short* y2lo = (unsigned short*)(ws + 9437184);
    unsigned*       bits = (unsigned*)(ws + 11010048);        // 8.4 MB
    unsigned short* wspl[3]  = {(unsigned short*)(ws + 13107200),
                                (unsigned short*)(ws + 13254656),
                                (unsigned short*)(ws + 13402112)};
    unsigned short* pwspl[3] = {(unsigned short*)(ws + 13549568),
                                (unsigned short*)(ws + 13623296),
                                (unsigned short*)(ws + 13697024)};
    unsigned short* xsF  = (unsigned short*)(ws + 13770752);  // 6.3 MB (786,432 f)
    float*          outpre  = (float*)(ws + 1572864);         // alias y1hi+y1mi
    float*          outpre2 = (float*)(ws + 14557184);        // fresh 12.6 MB
    unsigned short* outsT   = (unsigned short*)(ws + 4718592);// alias y1lo
    float* out = (float*)d_out;

    // 1) xs scan (both layouts, prefetched, 384 blocks) + weight split
    scan_and_split<<<dim3(816), 256, 0, stream>>>(x, xsT, xsF,
                                                  W_w, C2_*C_/4, wspl[0], wspl[1], wspl[2],
                                                  pw,  C_*C_/4, pwspl[0], pwspl[1], pwspl[2]);
    // 2) y = BN1(W @ xs): y1 stored fragment-major
    gemm1_mfma<<<dim3(1024), 256, 0, stream>>>(wspl[0], wspl[1], wspl[2], xsT,
                                               g1, b1, m1, v1,
                                               y1hi, y1mi, y1lo, y2hi, y2mi, y2lo);
    // 3) attn spikes: LDS-free, coalesced; bits transposed layout
    attn_spike_mfma<<<dim3(2048), 256, 0, stream>>>(y1hi, y1mi, y1lo, xsF, bits);
    // 4) outpre(+outpre2) = y2 @ spikes: split-K over l, prefetched staging
    attn_out_mfma<<<dim3(1024), 256, 0, stream>>>(y2hi, y2mi, y2lo, bits, outpre, outpre2);
    // 5) outs spikes = scan(outpre + outpre2) -> bf16 transposed (384 blocks)
    scan_transpose2<<<dim3(384), 256, 0, stream>>>(outpre, outpre2, outsT);
    // 6) out = BN2(proj @ outs) + x
    gemm2_mfma<<<dim3(64, 8), 256, 0, stream>>>(pwspl[0], pwspl[1], pwspl[2], outsT,
                                                g2, b2, m2, v2, x, out);
}